// Round 5
// baseline (1212.703 us; speedup 1.0000x reference)
//
#include <hip/hip_runtime.h>
#include <cstdint>
#include <cstddef>

// ---------------------------------------------------------------------------
// simBNN forward on MI355X.  Round 5:
//  - fc2/fc3 GEMMs retiled: 128x256 block, 4 waves of 64x128 (acc 4x8).
//    ds_read/MFMA 0.5 -> 0.375; MFMA per staged byte and per barrier 2x.
//    (Round 4 showed conflicts=0 yet flat time -> LDS-read+barrier bound.)
//  - softmax rewritten LDS-tiled & coalesced (was ~2 GB of strided LLC
//    traffic: 256-channel reduction at 20KB stride per thread).
//  - swizzle key (row>>1)&3 kept (verified: 0 bank conflicts).
// ---------------------------------------------------------------------------

typedef int      v4i  __attribute__((ext_vector_type(4)));
typedef float    v4f  __attribute__((ext_vector_type(4)));
typedef _Float16 v8h  __attribute__((ext_vector_type(8)));

#define EPS_BN 2e-5

__device__ __forceinline__ void g2l16(const void* g, void* l) {
  __builtin_amdgcn_global_load_lds((__attribute__((address_space(1))) void*)g,
                                   (__attribute__((address_space(3))) void*)l,
                                   16, 0, 0);
}

// ---------------------------------------------------------------------------
// conv1: x[8,3,211,211] fp32, w[96,3,11,11], stride 4, no pad -> y[8,96,51,51]
// ---------------------------------------------------------------------------
__global__ __launch_bounds__(256) void conv1_k(const float* __restrict__ x,
                                               const float* __restrict__ w,
                                               float* __restrict__ y) {
  const int bid = blockIdx.x;
  const int n = bid / 51, oh = bid % 51;
  const int tid = threadIdx.x, lane = tid & 63, wave = tid >> 6;
  __shared__ __align__(16) float xs[3 * 11 * 272];
  for (int i = tid; i < 3 * 11 * 272; i += 256) {
    int iw = i % 272;
    int t = i / 272;
    int kh = t % 11, ci = t / 11;
    float v = 0.f;
    if (iw < 211) v = x[((size_t)(n * 3 + ci) * 211 + (oh * 4 + kh)) * 211 + iw];
    xs[i] = v;
  }
  __syncthreads();
  const int ow = lane;
  const int g = blockIdx.y;
  {
    const int co0 = wave * 24 + g * 4;
    float a0 = 0.f, a1 = 0.f, a2 = 0.f, a3 = 0.f;
    for (int ci = 0; ci < 3; ++ci) {
#pragma unroll
      for (int kh = 0; kh < 11; ++kh) {
        const float* xr = xs + (ci * 11 + kh) * 272 + ow * 4;
        float4 q0 = *(const float4*)(xr);
        float4 q1 = *(const float4*)(xr + 4);
        float4 q2 = *(const float4*)(xr + 8);
        float xv[11] = {q0.x, q0.y, q0.z, q0.w, q1.x, q1.y,
                        q1.z, q1.w, q2.x, q2.y, q2.z};
        const float* wr = w + ((size_t)co0 * 3 + ci) * 121 + kh * 11;
#pragma unroll
        for (int kw = 0; kw < 11; ++kw) {
          float xvv = xv[kw];
          a0 = fmaf(xvv, wr[kw], a0);
          a1 = fmaf(xvv, wr[363 + kw], a1);
          a2 = fmaf(xvv, wr[726 + kw], a2);
          a3 = fmaf(xvv, wr[1089 + kw], a3);
        }
      }
    }
    if (ow < 51) {
      size_t ob = ((size_t)(n * 96 + co0) * 51 + oh) * 51 + ow;
      y[ob] = a0;
      y[ob + 2601] = a1;
      y[ob + 2 * 2601] = a2;
      y[ob + 3 * 2601] = a3;
    }
  }
}

// ---------------------------------------------------------------------------
// BN statistics
// ---------------------------------------------------------------------------
template <typename T>
__global__ __launch_bounds__(256) void bnstat_nchw_k(const T* __restrict__ y,
                                                     const float* __restrict__ g,
                                                     const float* __restrict__ bb,
                                                     float* __restrict__ par,
                                                     int C, int HW, int Nn) {
  const int c = blockIdx.x;
  double s = 0.0, q = 0.0;
  for (int n = 0; n < Nn; ++n) {
    const T* p = y + ((size_t)n * C + c) * HW;
    for (int r = threadIdx.x; r < HW; r += 256) {
      double v = (double)p[r];
      s += v;
      q += v * v;
    }
  }
  __shared__ double ss[256], qq[256];
  ss[threadIdx.x] = s;
  qq[threadIdx.x] = q;
  __syncthreads();
  for (int st = 128; st > 0; st >>= 1) {
    if (threadIdx.x < st) {
      ss[threadIdx.x] += ss[threadIdx.x + st];
      qq[threadIdx.x] += qq[threadIdx.x + st];
    }
    __syncthreads();
  }
  if (threadIdx.x == 0) {
    double P = (double)Nn * HW;
    double m = ss[0] / P, var = qq[0] / P - m * m;
    float inv = (float)(1.0 / sqrt(var + EPS_BN));
    float sc = g[c] * inv;
    par[c] = sc;
    par[512 + c] = bb[c] - (float)m * sc;
  }
}

template <typename T>
__global__ __launch_bounds__(256) void bnstat_nhwc_k(const T* __restrict__ y,
                                                     const float* __restrict__ g,
                                                     const float* __restrict__ bb,
                                                     float* __restrict__ par,
                                                     int C, int P) {
  const int c = blockIdx.x;
  double s = 0.0, q = 0.0;
  for (int p = threadIdx.x; p < P; p += 256) {
    double v = (double)y[(size_t)p * C + c];
    s += v;
    q += v * v;
  }
  __shared__ double ss[256], qq[256];
  ss[threadIdx.x] = s;
  qq[threadIdx.x] = q;
  __syncthreads();
  for (int st = 128; st > 0; st >>= 1) {
    if (threadIdx.x < st) {
      ss[threadIdx.x] += ss[threadIdx.x + st];
      qq[threadIdx.x] += qq[threadIdx.x + st];
    }
    __syncthreads();
  }
  if (threadIdx.x == 0) {
    double Pd = (double)P;
    double m = ss[0] / Pd, var = qq[0] / Pd - m * m;
    float inv = (float)(1.0 / sqrt(var + EPS_BN));
    float sc = g[c] * inv;
    par[c] = sc;
    par[512 + c] = bb[c] - (float)m * sc;
  }
}

// two-stage BN stats for F2 (i16, NCHW, C=256, HW=20480, Nn=8)
__global__ __launch_bounds__(256) void bnp16_k(const short* __restrict__ y,
                                               double* __restrict__ part) {
  const int c = blockIdx.x, n = blockIdx.y;
  const short* p = y + ((size_t)(n * 256 + c)) * 20480;
  long long s = 0, q = 0;
  for (int r = threadIdx.x; r < 20480; r += 256) {
    int v = p[r];
    s += v;
    q += (long long)v * v;
  }
  __shared__ long long ss[256], qq[256];
  ss[threadIdx.x] = s;
  qq[threadIdx.x] = q;
  __syncthreads();
  for (int st = 128; st > 0; st >>= 1) {
    if (threadIdx.x < st) {
      ss[threadIdx.x] += ss[threadIdx.x + st];
      qq[threadIdx.x] += qq[threadIdx.x + st];
    }
    __syncthreads();
  }
  if (threadIdx.x == 0) {
    part[(size_t)(n * 256 + c) * 2] = (double)ss[0];
    part[(size_t)(n * 256 + c) * 2 + 1] = (double)qq[0];
  }
}

__global__ __launch_bounds__(256) void bnf7_k(const double* __restrict__ part,
                                              const float* __restrict__ g,
                                              const float* __restrict__ bb,
                                              float* __restrict__ par) {
  int c = threadIdx.x;
  double s = 0.0, q = 0.0;
  for (int n = 0; n < 8; ++n) {
    s += part[(size_t)(n * 256 + c) * 2];
    q += part[(size_t)(n * 256 + c) * 2 + 1];
  }
  double P = 163840.0;
  double m = s / P, var = q / P - m * m;
  float inv = (float)(1.0 / sqrt(var + EPS_BN));
  float sc = g[c] * inv;
  par[c] = sc;
  par[512 + c] = bb[c] - (float)m * sc;
}

// ---------------------------------------------------------------------------
// pool/sign kernels
// ---------------------------------------------------------------------------
__global__ __launch_bounds__(256) void pool1sign_k(const float* __restrict__ y,
                                                   const float* __restrict__ par,
                                                   int8_t* __restrict__ o) {
  unsigned idx = blockIdx.x * 256 + threadIdx.x;
  if (idx >= 8u * 96 * 25 * 25) return;
  unsigned ow = idx % 25, t = idx / 25;
  unsigned oh = t % 25;
  t /= 25;
  unsigned c = t % 96, n = t / 96;
  float sc = par[c], sh = par[512 + c];
  const float* p = y + ((size_t)(n * 96 + c) * 51 + oh * 2) * 51 + ow * 2;
  float mx = -1e30f, mn = 1e30f;
#pragma unroll
  for (int kh = 0; kh < 3; ++kh)
#pragma unroll
    for (int kw = 0; kw < 3; ++kw) {
      float v = p[kh * 51 + kw];
      mx = fmaxf(mx, v);
      mn = fminf(mn, v);
    }
  float z = (sc >= 0.f ? sc * mx : sc * mn) + sh;
  o[((n * 25 + oh) * 25 + ow) * 96 + c] = (z > 0.f) ? 1 : 0;
}

__global__ __launch_bounds__(256) void poolsign_k(const short* __restrict__ y,
                                                  const float* __restrict__ par,
                                                  int8_t* __restrict__ o, int Nn,
                                                  int Hin, int C, int Hout) {
  unsigned idx = blockIdx.x * 256 + threadIdx.x;
  if (idx >= (unsigned)Nn * Hout * Hout * C) return;
  unsigned c = idx % C;
  unsigned t = idx / C;
  unsigned ow = t % Hout;
  t /= Hout;
  unsigned oh = t % Hout;
  unsigned n = t / Hout;
  const short* p = y + ((size_t)(n * Hin + oh * 2) * Hin + ow * 2) * C + c;
  int mx = -1000000, mn = 1000000;
#pragma unroll
  for (int kh = 0; kh < 3; ++kh)
#pragma unroll
    for (int kw = 0; kw < 3; ++kw) {
      int v = p[(kh * Hin + kw) * C];
      mx = max(mx, v);
      mn = min(mn, v);
    }
  float sc = par[c];
  float z = (sc >= 0.f ? sc * (float)mx : sc * (float)mn) + par[512 + c];
  o[idx] = (z > 0.f) ? 1 : ((z < 0.f) ? -1 : 0);
}

__global__ __launch_bounds__(256) void signk(const short* __restrict__ y,
                                             const float* __restrict__ par,
                                             int8_t* __restrict__ o, int total,
                                             int C) {
  unsigned idx = blockIdx.x * 256 + threadIdx.x;
  if (idx >= (unsigned)total) return;
  unsigned c = idx % C;
  float z = par[c] * (float)y[idx] + par[512 + c];
  o[idx] = (z > 0.f) ? 1 : ((z < 0.f) ? -1 : 0);
}

__global__ __launch_bounds__(256) void pool5sign_k(const short* __restrict__ y,
                                                   const float* __restrict__ par,
                                                   int8_t* __restrict__ o) {
  unsigned idx = blockIdx.x * 256 + threadIdx.x;
  if (idx >= 8u * 256 * 25) return;
  unsigned ow = idx % 5;
  unsigned t = idx / 5;
  unsigned oh = t % 5;
  t /= 5;
  unsigned c = t % 256, n = t / 256;
  const short* p = y + ((size_t)(n * 12 + oh * 2) * 12 + ow * 2) * 256 + c;
  int mx = -1000000, mn = 1000000;
#pragma unroll
  for (int kh = 0; kh < 3; ++kh)
#pragma unroll
    for (int kw = 0; kw < 3; ++kw) {
      int v = p[(kh * 12 + kw) * 256];
      mx = max(mx, v);
      mn = min(mn, v);
    }
  float sc = par[c];
  float z = (sc >= 0.f ? sc * (float)mx : sc * (float)mn) + par[512 + c];
  o[idx] = (z > 0.f) ? 1 : ((z < 0.f) ? -1 : 0);
}

// ---------------------------------------------------------------------------
// weight quantize
// ---------------------------------------------------------------------------
__global__ __launch_bounds__(256) void quantw_k(const float* __restrict__ w,
                                                int8_t* __restrict__ o, int Co,
                                                int Ci, int KHW, int K, int Kp) {
  unsigned idx = blockIdx.x * 256 + threadIdx.x;
  if (idx >= (unsigned)Co * Kp) return;
  unsigned k = idx % Kp;
  unsigned co = idx / Kp;
  int8_t v = 0;
  if (k < (unsigned)K) {
    unsigned tap = k / Ci, ci = k - tap * Ci;
    float f = w[((size_t)co * Ci + ci) * KHW + tap];
    v = (f > 0.f) ? 1 : ((f < 0.f) ? -1 : 0);
  }
  o[idx] = v;
}

__global__ __launch_bounds__(256) void quantwv_k(const float* __restrict__ w,
                                                 int8_t* __restrict__ o,
                                                 unsigned total4) {
  unsigned idx = blockIdx.x * 256 + threadIdx.x;
  if (idx >= total4) return;
  float4 f = ((const float4*)w)[idx];
  union { int8_t b[4]; int i; } u;
  u.b[0] = (f.x > 0.f) ? 1 : ((f.x < 0.f) ? -1 : 0);
  u.b[1] = (f.y > 0.f) ? 1 : ((f.y < 0.f) ? -1 : 0);
  u.b[2] = (f.z > 0.f) ? 1 : ((f.z < 0.f) ? -1 : 0);
  u.b[3] = (f.w > 0.f) ? 1 : ((f.w < 0.f) ? -1 : 0);
  ((int*)o)[idx] = u.i;
}

// ---------------------------------------------------------------------------
// im2col as 16B-chunk vector copy
// ---------------------------------------------------------------------------
__global__ __launch_bounds__(256) void im2colv_k(const int8_t* __restrict__ a,
                                                 int8_t* __restrict__ o, int Nn,
                                                 int H, int C, int KH, int pad,
                                                 int K, int Kp) {
  unsigned t = blockIdx.x * 256 + threadIdx.x;
  unsigned chunks = (unsigned)Kp >> 4;
  unsigned total = (unsigned)Nn * H * H * chunks;
  if (t >= total) return;
  unsigned kc = t % chunks;
  unsigned m = t / chunks;
  unsigned ow = m % H;
  unsigned tmp = m / H;
  unsigned oh = tmp % H;
  unsigned n = tmp / H;
  unsigned k0 = kc << 4;
  int4 v = {0, 0, 0, 0};
  if (k0 < (unsigned)K) {
    unsigned tap = k0 / C;
    unsigned ci = k0 - tap * C;
    unsigned kh = tap / KH, kw = tap - kh * KH;
    int ih = (int)oh - pad + (int)kh, iw = (int)ow - pad + (int)kw;
    if (ih >= 0 && ih < H && iw >= 0 && iw < H)
      v = *(const int4*)(a + (((n * H + ih) * H + iw) * C + ci));
  }
  *(int4*)(o + (size_t)m * Kp + k0) = v;
}

// ---------------------------------------------------------------------------
// i8 GEMM 128x256 block, BK=64, 16x16x64 MFMA, 4 waves of 64x128 (acc 4x8).
// LDS swizzle: physchunk = logicalchunk ^ ((row>>1)&3), realized on the
// global source address at staging; readers un-swizzle.  M%128==0, N%256==0.
// ---------------------------------------------------------------------------
__global__ __launch_bounds__(256) void gemm_i8_k(const int8_t* __restrict__ A,
                                                 const int8_t* __restrict__ B,
                                                 short* __restrict__ Cm, int M,
                                                 int N, int Kp) {
  __shared__ __align__(16) int8_t As[128 * 64];
  __shared__ __align__(16) int8_t Bs[256 * 64];
  const int tid = threadIdx.x;
  const int lane = tid & 63, wave = tid >> 6;
  const int m0 = blockIdx.x * 128, n0 = blockIdx.y * 256;
  const int wm = (wave >> 1) * 64, wn = (wave & 1) * 128;
  v4i acc[4][8];
#pragma unroll
  for (int r = 0; r < 4; ++r)
#pragma unroll
    for (int u = 0; u < 8; ++u) acc[r][u] = (v4i){0, 0, 0, 0};

  // staging slots: q=0,1 -> A rows 0..127; q=2..5 -> B rows 0..255
  int r_[6], g_[6];
#pragma unroll
  for (int q = 0; q < 6; ++q) {
    int idx = q * 256 + tid;
    int row = idx >> 2;
    r_[q] = (q < 2) ? row : (row - 128);
    g_[q] = (((idx & 3) ^ ((row >> 1) & 3)) << 4);
  }
  int aoff[4], boff[8];
#pragma unroll
  for (int r = 0; r < 4; ++r) {
    int m = wm + r * 16 + (lane & 15);
    aoff[r] = m * 64 + (((lane >> 4) ^ ((m >> 1) & 3)) << 4);
  }
#pragma unroll
  for (int u = 0; u < 8; ++u) {
    int n = wn + u * 16 + (lane & 15);
    boff[u] = n * 64 + (((lane >> 4) ^ ((n >> 1) & 3)) << 4);
  }

  for (int k0 = 0; k0 < Kp; k0 += 64) {
#pragma unroll
    for (int q = 0; q < 2; ++q) {
      int idx = q * 256 + tid;
      g2l16(A + (size_t)(m0 + r_[q]) * Kp + k0 + g_[q], As + idx * 16);
    }
#pragma unroll
    for (int q = 2; q < 6; ++q) {
      int idx = q * 256 + tid;
      g2l16(B + (size_t)(n0 + r_[q]) * Kp + k0 + g_[q], Bs + (idx - 512) * 16);
    }
    __syncthreads();
    v4i af[4], bf[8];
#pragma unroll
    for (int r = 0; r < 4; ++r) af[r] = *(const v4i*)(As + aoff[r]);
#pragma unroll
    for (int u = 0; u < 8; ++u) bf[u] = *(const v4i*)(Bs + boff[u]);
#pragma unroll
    for (int r = 0; r < 4; ++r)
#pragma unroll
      for (int u = 0; u < 8; ++u)
        acc[r][u] = __builtin_amdgcn_mfma_i32_16x16x64_i8(af[r], bf[u],
                                                          acc[r][u], 0, 0, 0);
    __syncthreads();
  }
  const int colD = lane & 15, rowD = (lane >> 4) * 4;
#pragma unroll
  for (int r = 0; r < 4; ++r)
#pragma unroll
    for (int u = 0; u < 8; ++u) {
      int n = n0 + wn + u * 16 + colD;
#pragma unroll
      for (int e = 0; e < 4; ++e) {
        int m = m0 + wm + r * 16 + rowD + e;
        if (m < M) Cm[(size_t)m * N + n] = (short)acc[r][u][e];
      }
    }
}

// ---------------------------------------------------------------------------
// i8 GEMM 64x64 tile (conv GEMMs): unchanged from round 4 (conflict-free).
// ---------------------------------------------------------------------------
__global__ __launch_bounds__(256) void gemm_i8_64k(const int8_t* __restrict__ A,
                                                   const int8_t* __restrict__ B,
                                                   short* __restrict__ Cm, int M,
                                                   int N, int Kp) {
  __shared__ __align__(16) int8_t As[64 * 64];
  __shared__ __align__(16) int8_t Bs[64 * 64];
  const int tid = threadIdx.x;
  const int lane = tid & 63, wave = tid >> 6;
  const int m0 = blockIdx.x * 64, n0 = blockIdx.y * 64;
  const int wm = (wave >> 1) * 32, wn = (wave & 1) * 32;
  v4i acc[2][2];
#pragma unroll
  for (int r = 0; r < 2; ++r)
#pragma unroll
    for (int u = 0; u < 2; ++u) acc[r][u] = (v4i){0, 0, 0, 0};

  const int rs = tid >> 2;
  const int gsw = (((tid & 3) ^ ((rs >> 1) & 3)) << 4);
  int aoff[2], boff[2];
#pragma unroll
  for (int r = 0; r < 2; ++r) {
    int m = wm + r * 16 + (lane & 15);
    aoff[r] = m * 64 + (((lane >> 4) ^ ((m >> 1) & 3)) << 4);
    int n = wn + r * 16 + (lane & 15);
    boff[r] = n * 64 + (((lane >> 4) ^ ((n >> 1) & 3)) << 4);
  }

  for (int k0 = 0; k0 < Kp; k0 += 64) {
    g2l16(A + (size_t)(m0 + rs) * Kp + k0 + gsw, As + tid * 16);
    g2l16(B + (size_t)(n0 + rs) * Kp + k0 + gsw, Bs + tid * 16);
    __syncthreads();
    v4i af[2], bf[2];
#pragma unroll
    for (int r = 0; r < 2; ++r) {
      af[r] = *(const v4i*)(As + aoff[r]);
      bf[r] = *(const v4i*)(Bs + boff[r]);
    }
#pragma unroll
    for (int r = 0; r < 2; ++r)
#pragma unroll
      for (int u = 0; u < 2; ++u)
        acc[r][u] = __builtin_amdgcn_mfma_i32_16x16x64_i8(af[r], bf[u],
                                                          acc[r][u], 0, 0, 0);
    __syncthreads();
  }
  const int colD = lane & 15, rowD = (lane >> 4) * 4;
#pragma unroll
  for (int r = 0; r < 2; ++r)
#pragma unroll
    for (int u = 0; u < 2; ++u) {
      int n = n0 + wn + u * 16 + colD;
#pragma unroll
      for (int e = 0; e < 4; ++e) {
        int m = m0 + wm + r * 16 + rowD + e;
        if (m < M) Cm[(size_t)m * N + n] = (short)acc[r][u][e];
      }
    }
}

// ---------------------------------------------------------------------------
// f16 GEMM 128x256 block (fc3), 16x16x32 MFMA, 4 waves of 64x128 (acc 4x8).
// ---------------------------------------------------------------------------
__global__ __launch_bounds__(256) void gemm_f16_k(const _Float16* __restrict__ A,
                                                  const _Float16* __restrict__ B,
                                                  float* __restrict__ out,
                                                  const float* __restrict__ bias,
                                                  int M, int Nout, int K) {
  __shared__ __align__(16) int8_t As[128 * 64];
  __shared__ __align__(16) int8_t Bs[256 * 64];
  const int tid = threadIdx.x;
  const int lane = tid & 63, wave = tid >> 6;
  const int m0 = blockIdx.x * 128, n0 = blockIdx.y * 256;
  const int wm = (wave >> 1) * 64, wn = (wave & 1) * 128;
  const int KpB = K * 2;
  v4f acc[4][8];
#pragma unroll
  for (int r = 0; r < 4; ++r)
#pragma unroll
    for (int u = 0; u < 8; ++u) acc[r][u] = (v4f){0.f, 0.f, 0.f, 0.f};

  int r_[6], g_[6];
#pragma unroll
  for (int q = 0; q < 6; ++q) {
    int idx = q * 256 + tid;
    int row = idx >> 2;
    r_[q] = (q < 2) ? row : (row - 128);
    g_[q] = (((idx & 3) ^ ((row >> 1) & 3)) << 4);
  }
  int aoff[4], boff[8];
#pragma unroll
  for (int r = 0; r < 4; ++r) {
    int m = wm + r * 16 + (lane & 15);
    aoff[r] = m * 64 + (((lane >> 4) ^ ((m >> 1) & 3)) << 4);
  }
#pragma unroll
  for (int u = 0; u < 8; ++u) {
    int n = wn + u * 16 + (lane & 15);
    boff[u] = n * 64 + (((lane >> 4) ^ ((n >> 1) & 3)) << 4);
  }

  const int8_t* Ab = (const int8_t*)A;
  const int8_t* Bb = (const int8_t*)B;
  for (int k0 = 0; k0 < KpB; k0 += 64) {
#pragma unroll
    for (int q = 0; q < 2; ++q) {
      int idx = q * 256 + tid;
      g2l16(Ab + (size_t)(m0 + r_[q]) * KpB + k0 + g_[q], As + idx * 16);
    }
#pragma unroll
    for (int q = 2; q < 6; ++q) {
      int idx = q * 256 + tid;
      g2l16(Bb + (size_t)(n0 + r_[q]) * KpB + k0 + g_[q], Bs + (idx - 512) * 16);
    }
    __syncthreads();
    v8h af[4], bf[8];
#pragma unroll
    for (int r = 0; r < 4; ++r) af[r] = *(const v8h*)(As + aoff[r]);
#pragma unroll
    for (int u = 0; u < 8; ++u) bf[u] = *(const v8h*)(Bs + boff[u]);
#pragma unroll
    for (int r = 0; r < 4; ++r)
#pragma unroll
      for (int u = 0; u < 8; ++u)
        acc[r][u] = __builtin_amdgcn_mfma_f32_16x16x32_f16(af[r], bf[u],
                                                           acc[r][u], 0, 0, 0);
    __syncthreads();
  }
  const int colD = lane & 15, rowD = (lane >> 4) * 4;
#pragma unroll
  for (int r = 0; r < 4; ++r)
#pragma unroll
    for (int u = 0; u < 8; ++u) {
      int n = n0 + wn + u * 16 + colD;
      if (n < Nout) {
        float bv = bias[n];
#pragma unroll
        for (int e = 0; e < 4; ++e) {
          int m = m0 + wm + r * 16 + rowD + e;
          if (m < M) out[(size_t)m * Nout + n] = acc[r][u][e] + bv;
        }
      }
    }
}

// ---------------------------------------------------------------------------
// fc1 BN6 stats via 5x5 Gram matrix + fused fc1+threshold
// ---------------------------------------------------------------------------
__global__ __launch_bounds__(256) void gram_k(const int8_t* __restrict__ wq1,
                                              int* __restrict__ gm) {
  __shared__ int sg[30];
  if (threadIdx.x < 30) sg[threadIdx.x] = 0;
  __syncthreads();
  int acc[30];
#pragma unroll
  for (int i = 0; i < 30; ++i) acc[i] = 0;
  for (int j = threadIdx.x; j < 4096; j += 256) {
    const int8_t* w = wq1 + j * 5;
    int v[5];
#pragma unroll
    for (int k = 0; k < 5; ++k) v[k] = w[k];
#pragma unroll
    for (int k = 0; k < 5; ++k) {
      acc[k] += v[k];
#pragma unroll
      for (int l = 0; l < 5; ++l) acc[5 + k * 5 + l] += v[k] * v[l];
    }
  }
#pragma unroll
  for (int i = 0; i < 30; ++i) atomicAdd(&sg[i], acc[i]);
  __syncthreads();
  if (threadIdx.x < 30) gm[threadIdx.x] = sg[threadIdx.x];
}

__global__ __launch_bounds__(256) void par6_k(const int8_t* __restrict__ s5,
                                              const int* __restrict__ gm,
                                              const float* __restrict__ g,
                                              const float* __restrict__ bb,
                                              float* __restrict__ par) {
  int c = threadIdx.x;
  long long s = 0, q = 0;
  for (int n = 0; n < 8; ++n)
    for (int i = 0; i < 5; ++i) {
      const int8_t* a = s5 + ((size_t)((n * 256 + c) * 5 + i)) * 5;
      int av[5];
#pragma unroll
      for (int k = 0; k < 5; ++k) av[k] = a[k];
      int ds = 0, dq = 0;
#pragma unroll
      for (int k = 0; k < 5; ++k) {
        ds += av[k] * gm[k];
#pragma unroll
        for (int l = 0; l < 5; ++l) dq += av[k] * av[l] * gm[5 + k * 5 + l];
      }
      s += ds;
      q += dq;
    }
  double P = 163840.0;
  double m = (double)s / P, var = (double)q / P - m * m;
  float inv = (float)(1.0 / sqrt(var + EPS_BN));
  float sc = g[c] * inv;
  par[c] = sc;
  par[512 + c] = bb[c] - (float)m * sc;
}

__global__ __launch_bounds__(256) void fc1f_k(const int8_t* __restrict__ s5,
                                              const int8_t* __restrict__ wq1,
                                              const float* __restrict__ par,
                                              int8_t* __restrict__ f1) {
  unsigned idx = blockIdx.x * 256 + threadIdx.x;
  if (idx >= 10240u * 256) return;
  unsigned m = idx >> 8, jg = idx & 255;
  unsigned c = (m / 5) & 255;
  float sc = par[c], sh = par[512 + c];
  const int8_t* ap = s5 + m * 5;
  int a0 = ap[0], a1 = ap[1], a2 = ap[2], a3 = ap[3], a4 = ap[4];
  int8_t wb[80];
  const int4* wp = (const int4*)(wq1 + jg * 80);
#pragma unroll
  for (int qq = 0; qq < 5; ++qq) *(int4*)(wb + qq * 16) = wp[qq];
  union { int8_t b[16]; int4 v; } ov;
#pragma unroll
  for (int t = 0; t < 16; ++t) {
    int d = a0 * wb[t * 5] + a1 * wb[t * 5 + 1] + a2 * wb[t * 5 + 2] +
            a3 * wb[t * 5 + 3] + a4 * wb[t * 5 + 4];
    float z = sc * (float)d + sh;
    ov.b[t] = (z > 0.f) ? 1 : 0;
  }
  *(int4*)(f1 + (size_t)m * 4096 + jg * 16) = ov.v;
}

// BN7 + relu -> f16, in-place, vectorized x8
__global__ __launch_bounds__(256) void x7v_k(short* __restrict__ f2,
                                             const float* __restrict__ par) {
  unsigned idx = blockIdx.x * 256 + threadIdx.x;
  if (idx >= 10240u * 4096 / 8) return;
  unsigned base8 = idx * 8;
  unsigned c = (base8 / 20480) & 255;
  float sc = par[c], sh = par[512 + c];
  union { int4 v; short s[8]; } in;
  in.v = *(int4*)(f2 + (size_t)base8);
  union { int4 v; _Float16 h[8]; } outv;
#pragma unroll
  for (int t = 0; t < 8; ++t) {
    float z = sc * (float)in.s[t] + sh;
    if (z < 0.f) z = 0.f;
    outv.h[t] = (_Float16)z;
  }
  *(int4*)((_Float16*)f2 + (size_t)base8) = outv.v;
}

__global__ __launch_bounds__(256) void w3h_k(const float* __restrict__ w,
                                             _Float16* __restrict__ o) {
  unsigned idx = blockIdx.x * 256 + threadIdx.x;
  if (idx >= 1024u * 4096) return;
  unsigned j = idx >> 12;
  o[idx] = (j < 1000) ? (_Float16)w[idx] : (_Float16)0.f;
}

// ---------------------------------------------------------------------------
// softmax over dim 1 (256 channels) on [8,256,5,1000] f32, LDS-tiled,
// coalesced. block = (b*5+i, jtile); tile = 256 c x 32 j.
// ---------------------------------------------------------------------------
__global__ __launch_bounds__(256) void softmax_k(float* __restrict__ o) {
  __shared__ float tile[256][33];
  __shared__ float red[8][32];
  __shared__ float mxs[32], invs[32];
  const int bi = blockIdx.x;            // b*5 + i
  const int jt = blockIdx.y;            // 0..31
  const int b = bi / 5, i = bi % 5;
  float* base = o + ((size_t)(b * 256) * 5 + i) * 1000;  // + c*5000 + j
  const int t = threadIdx.x;
  const int jl = t & 31, part = t >> 5;  // part 0..7
  const int j = jt * 32 + jl;
  const bool ok = (j < 1000);
  // load (coalesced: consecutive t -> consecutive j within a c-row)
  for (int cg = 0; cg < 32; ++cg) {
    int c = cg * 8 + part;
    tile[c][jl] = ok ? base[(size_t)c * 5000 + j] : 0.f;
  }
  __syncthreads();
  // max over c (8 partials of 32 each)
  float pm = -1e30f;
#pragma unroll 4
  for (int cc = 0; cc < 32; ++cc) pm = fmaxf(pm, tile[part * 32 + cc][jl]);
  red[part][jl] = pm;
  __syncthreads();
  if (part == 0) {
    float m = red[0][jl];
#pragma unroll
    for (int p = 1; p < 8; ++p) m = fmaxf(m, red[p][jl]);
    mxs[jl] = m;
  }
  __syncthreads();
  float mx = mxs[jl];
  float ps = 0.f;
#pragma unroll 4
  for (int cc = 0; cc < 32; ++cc) ps += expf(tile[part * 32 + cc][jl] - mx);
  red[part][jl] = ps;
  __syncthreads();
  if (part == 0) {
    float s = red[0][jl];
#pragma unroll
    for (int p = 1; p < 8; ++p) s += red[p][jl];
    invs[jl] = 1.f / s;
  }
  __syncthreads();
  float inv = invs[jl];
  for (int cg = 0; cg < 32; ++cg) {
    int c = cg * 8 + part;
    if (ok) base[(size_t)c * 5000 + j] = expf(tile[c][jl] - mx) * inv;
  }
}

// ---------------------------------------------------------------------------
// launcher
// ---------------------------------------------------------------------------
static inline unsigned gs(size_t n) { return (unsigned)((n + 255) / 256); }

extern "C" void kernel_launch(void* const* d_in, const int* in_sizes, int n_in,
                              void* d_out, int out_size, void* d_ws,
                              size_t ws_size, hipStream_t stream) {
  (void)in_sizes; (void)n_in; (void)out_size; (void)ws_size;
  const float* x    = (const float*)d_in[0];
  const float* w1   = (const float*)d_in[1];
  const float* bn1g = (const float*)d_in[3];
  const float* bn1b = (const float*)d_in[4];
  const float* w2   = (const float*)d_in[5];
  const float* bn2g = (const float*)d_in[7];
  const float* bn2b = (const float*)d_in[8];
  const float* w3   = (const float*)d_in[9];
  const float* bn3g = (const float*)d_in[11];
  const float* bn3b = (const float*)d_in[12];
  const float* w4   = (const float*)d_in[13];
  const float* bn4g = (const float*)d_in[15];
  const float* bn4b = (const float*)d_in[16];
  const float* w5   = (const float*)d_in[17];
  const float* bn5g = (const float*)d_in[19];
  const float* bn5b = (const float*)d_in[20];
  const float* fc1w = (const float*)d_in[21];
  const float* bn6g = (const float*)d_in[22];
  const float* bn6b = (const float*)d_in[23];
  const float* fc2w = (const float*)d_in[24];
  const float* bn7g = (const float*)d_in[25];
  const float* bn7b = (const float*)d_in[26];
  const float* fc3w = (const float*)d_in[27];
  const float* fc3b = (const float*)d_in[28];
  float* out = (float*)d_out;

  char* ws = (char*)d_ws;
  size_t off = 0;
  auto alloc = [&](size_t bytes) -> void* {
    off = (off + 255) & ~(size_t)255;
    void* p = ws + off;
    off += bytes;
    return p;
  };
  float*   Y1   = (float*)alloc((size_t)8 * 96 * 51 * 51 * 4);
  int8_t*  S1   = (int8_t*)alloc((size_t)8 * 25 * 25 * 96);
  int8_t*  IM   = (int8_t*)alloc((size_t)5120 * 2432);
  short*   Y2   = (short*)alloc((size_t)5056 * 256 * 2);
  int8_t*  S2   = (int8_t*)alloc((size_t)1152 * 256);
  short*   Y3   = (short*)alloc((size_t)1152 * 384 * 2);
  int8_t*  S3   = (int8_t*)alloc((size_t)1152 * 384);
  short*   Y4   = (short*)alloc((size_t)1152 * 384 * 2);
  int8_t*  S4   = (int8_t*)alloc((size_t)1152 * 384);
  short*   Y5   = (short*)alloc((size_t)1152 * 256 * 2);
  int8_t*  S5   = (int8_t*)alloc((size_t)8 * 256 * 25);
  int8_t*  WQ2  = (int8_t*)alloc((size_t)256 * 2432);
  int8_t*  WQ3  = (int8_t*)alloc((size_t)384 * 2304);
  int8_t*  WQ4  = (int8_t*)alloc((size_t)384 * 3456);
  int8_t*  WQ5  = (int8_t*)alloc((size_t)256 * 3456);
  int8_t*  WQ1  = (int8_t*)alloc((size_t)4096 * 5);
  int8_t*  WQF2 = (int8_t*)alloc((size_t)4096 * 4096);
  int8_t*  F1   = (int8_t*)alloc((size_t)10240 * 4096);
  short*   F2   = (short*)alloc((size_t)10240 * 4096 * 2);
  _Float16* W3H = (_Float16*)alloc((size_t)1024 * 4096 * 2);
  float*   PAR  = (float*)alloc((size_t)7 * 1024 * 4);
  int*     GM   = (int*)alloc(32 * 4);
  double*  PART = (double*)alloc((size_t)2048 * 2 * 8);
  float* par1 = PAR;
  float* par2 = PAR + 1024;
  float* par3 = PAR + 2048;
  float* par4 = PAR + 3072;
  float* par5 = PAR + 4096;
  float* par6 = PAR + 5120;
  float* par7 = PAR + 6144;

  // ---- weight prep ----
  quantw_k<<<gs((size_t)256 * 2432), 256, 0, stream>>>(w2, WQ2, 256, 96, 25, 2400, 2432);
  quantw_k<<<gs((size_t)384 * 2304), 256, 0, stream>>>(w3, WQ3, 384, 256, 9, 2304, 2304);
  quantw_k<<<gs((size_t)384 * 3456), 256, 0, stream>>>(w4, WQ4, 384, 384, 9, 3456, 3456);
  quantw_k<<<gs((size_t)256 * 3456), 256, 0, stream>>>(w5, WQ5, 256, 384, 9, 3456, 3456);
  quantw_k<<<gs((size_t)4096 * 5), 256, 0, stream>>>(fc1w, WQ1, 4096, 5, 1, 5, 5);
  quantwv_k<<<gs((size_t)4096 * 1024), 256, 0, stream>>>(fc2w, WQF2, 4096u * 1024);
  w3h_k<<<gs((size_t)1024 * 4096), 256, 0, stream>>>(fc3w, W3H);

  // ---- conv1 + BN1 + relu + pool + sign ----
  conv1_k<<<dim3(8 * 51, 6), 256, 0, stream>>>(x, w1, Y1);
  bnstat_nchw_k<float><<<dim3(96), 256, 0, stream>>>(Y1, bn1g, bn1b, par1, 96, 2601, 8);
  pool1sign_k<<<gs((size_t)8 * 96 * 625), 256, 0, stream>>>(Y1, par1, S1);

  // ---- conv2 ----
  im2colv_k<<<gs((size_t)5000 * 152), 256, 0, stream>>>(S1, IM, 8, 25, 96, 5, 2, 2400, 2432);
  gemm_i8_64k<<<dim3(79, 4), 256, 0, stream>>>(IM, WQ2, Y2, 5000, 256, 2432);
  bnstat_nhwc_k<short><<<dim3(256), 256, 0, stream>>>(Y2, bn2g, bn2b, par2, 256, 5000);
  poolsign_k<<<gs((size_t)8 * 144 * 256), 256, 0, stream>>>(Y2, par2, S2, 8, 25, 256, 12);

  // ---- conv3 ----
  im2colv_k<<<gs((size_t)1152 * 144), 256, 0, stream>>>(S2, IM, 8, 12, 256, 3, 1, 2304, 2304);
  gemm_i8_64k<<<dim3(18, 6), 256, 0, stream>>>(IM, WQ3, Y3, 1152, 384, 2304);
  bnstat_nhwc_k<short><<<dim3(384), 256, 0, stream>>>(Y3, bn3g, bn3b, par3, 384, 1152);
  signk<<<gs((size_t)1152 * 384), 256, 0, stream>>>(Y3, par3, S3, 1152 * 384, 384);

  // ---- conv4 ----
  im2colv_k<<<gs((size_t)1152 * 216), 256, 0, stream>>>(S3, IM, 8, 12, 384, 3, 1, 3456, 3456);
  gemm_i8_64k<<<dim3(18, 6), 256, 0, stream>>>(IM, WQ4, Y4, 1152, 384, 3456);
  bnstat_nhwc_k<short><<<dim3(384), 256, 0, stream>>>(Y4, bn4g, bn4b, par4, 384, 1152);
  signk<<<gs((size_t)1152 * 384), 256, 0, stream>>>(Y4, par4, S4, 1152 * 384, 384);

  // ---- conv5 ----
  im2colv_k<<<gs((size_t)1152 * 216), 256, 0, stream>>>(S4, IM, 8, 12, 384, 3, 1, 3456, 3456);
  gemm_i8_64k<<<dim3(18, 4), 256, 0, stream>>>(IM, WQ5, Y5, 1152, 256, 3456);
  bnstat_nhwc_k<short><<<dim3(256), 256, 0, stream>>>(Y5, bn5g, bn5b, par5, 256, 1152);
  pool5sign_k<<<gs((size_t)8 * 256 * 25), 256, 0, stream>>>(Y5, par5, S5);

  // ---- fc1 ----
  gram_k<<<dim3(1), 256, 0, stream>>>(WQ1, GM);
  par6_k<<<dim3(1), 256, 0, stream>>>(S5, GM, bn6g, bn6b, par6);
  fc1f_k<<<gs((size_t)10240 * 256), 256, 0, stream>>>(S5, WQ1, par6, F1);

  // ---- fc2 ----
  gemm_i8_k<<<dim3(80, 16), 256, 0, stream>>>(F1, WQF2, F2, 10240, 4096, 4096);
  bnp16_k<<<dim3(256, 8), 256, 0, stream>>>(F2, PART);
  bnf7_k<<<dim3(1), 256, 0, stream>>>(PART, bn7g, bn7b, par7);
  x7v_k<<<gs((size_t)10240 * 512), 256, 0, stream>>>(F2, par7);

  // ---- fc3 + softmax ----
  gemm_f16_k<<<dim3(80, 4), 256, 0, stream>>>((const _Float16*)F2, W3H, out, fc3b,
                                              10240, 1000, 4096);
  softmax_k<<<dim3(40, 32), 256, 0, stream>>>(out);
}

// Round 6
// 999.607 us; speedup vs baseline: 1.2132x; 1.2132x over previous
//
#include <hip/hip_runtime.h>
#include <cstdint>
#include <cstddef>

// ---------------------------------------------------------------------------
// simBNN forward on MI355X.  Round 6:
//  - fc2/fc3 GEMMs reverted to round-4 known-good 128x128 tiles (4x4 acc,
//    grid 1280 / 640 blocks).  Round 5's 128x256 cut fc3's grid to 320
//    blocks -> 1.25 blocks/CU -> latency-exposed K-loop (306 us, 11% mfma).
//    fc2 sits at the m97 structural plateau (~33% MfmaUtil) -- stop retiling.
//  - conv3/4/5 GEMMs: split-K via blockIdx.z (slices sized so partials fit
//    i16); consumers (bnstat/sign/pool) sum the slices.  Grids 108->432 etc.
//  - LDS-tiled coalesced softmax kept (round 5).
// ---------------------------------------------------------------------------

typedef int      v4i  __attribute__((ext_vector_type(4)));
typedef float    v4f  __attribute__((ext_vector_type(4)));
typedef _Float16 v8h  __attribute__((ext_vector_type(8)));

#define EPS_BN 2e-5

__device__ __forceinline__ void g2l16(const void* g, void* l) {
  __builtin_amdgcn_global_load_lds((__attribute__((address_space(1))) void*)g,
                                   (__attribute__((address_space(3))) void*)l,
                                   16, 0, 0);
}

// ---------------------------------------------------------------------------
// conv1: x[8,3,211,211] fp32, w[96,3,11,11], stride 4, no pad -> y[8,96,51,51]
// ---------------------------------------------------------------------------
__global__ __launch_bounds__(256) void conv1_k(const float* __restrict__ x,
                                               const float* __restrict__ w,
                                               float* __restrict__ y) {
  const int bid = blockIdx.x;
  const int n = bid / 51, oh = bid % 51;
  const int tid = threadIdx.x, lane = tid & 63, wave = tid >> 6;
  __shared__ __align__(16) float xs[3 * 11 * 272];
  for (int i = tid; i < 3 * 11 * 272; i += 256) {
    int iw = i % 272;
    int t = i / 272;
    int kh = t % 11, ci = t / 11;
    float v = 0.f;
    if (iw < 211) v = x[((size_t)(n * 3 + ci) * 211 + (oh * 4 + kh)) * 211 + iw];
    xs[i] = v;
  }
  __syncthreads();
  const int ow = lane;
  const int g = blockIdx.y;
  {
    const int co0 = wave * 24 + g * 4;
    float a0 = 0.f, a1 = 0.f, a2 = 0.f, a3 = 0.f;
    for (int ci = 0; ci < 3; ++ci) {
#pragma unroll
      for (int kh = 0; kh < 11; ++kh) {
        const float* xr = xs + (ci * 11 + kh) * 272 + ow * 4;
        float4 q0 = *(const float4*)(xr);
        float4 q1 = *(const float4*)(xr + 4);
        float4 q2 = *(const float4*)(xr + 8);
        float xv[11] = {q0.x, q0.y, q0.z, q0.w, q1.x, q1.y,
                        q1.z, q1.w, q2.x, q2.y, q2.z};
        const float* wr = w + ((size_t)co0 * 3 + ci) * 121 + kh * 11;
#pragma unroll
        for (int kw = 0; kw < 11; ++kw) {
          float xvv = xv[kw];
          a0 = fmaf(xvv, wr[kw], a0);
          a1 = fmaf(xvv, wr[363 + kw], a1);
          a2 = fmaf(xvv, wr[726 + kw], a2);
          a3 = fmaf(xvv, wr[1089 + kw], a3);
        }
      }
    }
    if (ow < 51) {
      size_t ob = ((size_t)(n * 96 + co0) * 51 + oh) * 51 + ow;
      y[ob] = a0;
      y[ob + 2601] = a1;
      y[ob + 2 * 2601] = a2;
      y[ob + 3 * 2601] = a3;
    }
  }
}

// ---------------------------------------------------------------------------
// BN statistics
// ---------------------------------------------------------------------------
template <typename T>
__global__ __launch_bounds__(256) void bnstat_nchw_k(const T* __restrict__ y,
                                                     const float* __restrict__ g,
                                                     const float* __restrict__ bb,
                                                     float* __restrict__ par,
                                                     int C, int HW, int Nn) {
  const int c = blockIdx.x;
  double s = 0.0, q = 0.0;
  for (int n = 0; n < Nn; ++n) {
    const T* p = y + ((size_t)n * C + c) * HW;
    for (int r = threadIdx.x; r < HW; r += 256) {
      double v = (double)p[r];
      s += v;
      q += v * v;
    }
  }
  __shared__ double ss[256], qq[256];
  ss[threadIdx.x] = s;
  qq[threadIdx.x] = q;
  __syncthreads();
  for (int st = 128; st > 0; st >>= 1) {
    if (threadIdx.x < st) {
      ss[threadIdx.x] += ss[threadIdx.x + st];
      qq[threadIdx.x] += qq[threadIdx.x + st];
    }
    __syncthreads();
  }
  if (threadIdx.x == 0) {
    double P = (double)Nn * HW;
    double m = ss[0] / P, var = qq[0] / P - m * m;
    float inv = (float)(1.0 / sqrt(var + EPS_BN));
    float sc = g[c] * inv;
    par[c] = sc;
    par[512 + c] = bb[c] - (float)m * sc;
  }
}

// NHWC stats over S split-K slices: value(p,c) = sum_s y[s*P*C + p*C + c]
__global__ __launch_bounds__(256) void bnstat_nhwc_k(const short* __restrict__ y,
                                                     const float* __restrict__ g,
                                                     const float* __restrict__ bb,
                                                     float* __restrict__ par,
                                                     int C, int P, int S) {
  const int c = blockIdx.x;
  double s = 0.0, q = 0.0;
  const size_t MN = (size_t)P * C;
  for (int p = threadIdx.x; p < P; p += 256) {
    int v = 0;
    for (int sl = 0; sl < S; ++sl) v += y[sl * MN + (size_t)p * C + c];
    double dv = (double)v;
    s += dv;
    q += dv * dv;
  }
  __shared__ double ss[256], qq[256];
  ss[threadIdx.x] = s;
  qq[threadIdx.x] = q;
  __syncthreads();
  for (int st = 128; st > 0; st >>= 1) {
    if (threadIdx.x < st) {
      ss[threadIdx.x] += ss[threadIdx.x + st];
      qq[threadIdx.x] += qq[threadIdx.x + st];
    }
    __syncthreads();
  }
  if (threadIdx.x == 0) {
    double Pd = (double)P;
    double m = ss[0] / Pd, var = qq[0] / Pd - m * m;
    float inv = (float)(1.0 / sqrt(var + EPS_BN));
    float sc = g[c] * inv;
    par[c] = sc;
    par[512 + c] = bb[c] - (float)m * sc;
  }
}

// two-stage BN stats for F2 (i16, NCHW, C=256, HW=20480, Nn=8)
__global__ __launch_bounds__(256) void bnp16_k(const short* __restrict__ y,
                                               double* __restrict__ part) {
  const int c = blockIdx.x, n = blockIdx.y;
  const short* p = y + ((size_t)(n * 256 + c)) * 20480;
  long long s = 0, q = 0;
  for (int r = threadIdx.x; r < 20480; r += 256) {
    int v = p[r];
    s += v;
    q += (long long)v * v;
  }
  __shared__ long long ss[256], qq[256];
  ss[threadIdx.x] = s;
  qq[threadIdx.x] = q;
  __syncthreads();
  for (int st = 128; st > 0; st >>= 1) {
    if (threadIdx.x < st) {
      ss[threadIdx.x] += ss[threadIdx.x + st];
      qq[threadIdx.x] += qq[threadIdx.x + st];
    }
    __syncthreads();
  }
  if (threadIdx.x == 0) {
    part[(size_t)(n * 256 + c) * 2] = (double)ss[0];
    part[(size_t)(n * 256 + c) * 2 + 1] = (double)qq[0];
  }
}

__global__ __launch_bounds__(256) void bnf7_k(const double* __restrict__ part,
                                              const float* __restrict__ g,
                                              const float* __restrict__ bb,
                                              float* __restrict__ par) {
  int c = threadIdx.x;
  double s = 0.0, q = 0.0;
  for (int n = 0; n < 8; ++n) {
    s += part[(size_t)(n * 256 + c) * 2];
    q += part[(size_t)(n * 256 + c) * 2 + 1];
  }
  double P = 163840.0;
  double m = s / P, var = q / P - m * m;
  float inv = (float)(1.0 / sqrt(var + EPS_BN));
  float sc = g[c] * inv;
  par[c] = sc;
  par[512 + c] = bb[c] - (float)m * sc;
}

// ---------------------------------------------------------------------------
// pool/sign kernels (split-K aware where needed)
// ---------------------------------------------------------------------------
__global__ __launch_bounds__(256) void pool1sign_k(const float* __restrict__ y,
                                                   const float* __restrict__ par,
                                                   int8_t* __restrict__ o) {
  unsigned idx = blockIdx.x * 256 + threadIdx.x;
  if (idx >= 8u * 96 * 25 * 25) return;
  unsigned ow = idx % 25, t = idx / 25;
  unsigned oh = t % 25;
  t /= 25;
  unsigned c = t % 96, n = t / 96;
  float sc = par[c], sh = par[512 + c];
  const float* p = y + ((size_t)(n * 96 + c) * 51 + oh * 2) * 51 + ow * 2;
  float mx = -1e30f, mn = 1e30f;
#pragma unroll
  for (int kh = 0; kh < 3; ++kh)
#pragma unroll
    for (int kw = 0; kw < 3; ++kw) {
      float v = p[kh * 51 + kw];
      mx = fmaxf(mx, v);
      mn = fminf(mn, v);
    }
  float z = (sc >= 0.f ? sc * mx : sc * mn) + sh;
  o[((n * 25 + oh) * 25 + ow) * 96 + c] = (z > 0.f) ? 1 : 0;
}

__global__ __launch_bounds__(256) void poolsign_k(const short* __restrict__ y,
                                                  const float* __restrict__ par,
                                                  int8_t* __restrict__ o, int Nn,
                                                  int Hin, int C, int Hout) {
  unsigned idx = blockIdx.x * 256 + threadIdx.x;
  if (idx >= (unsigned)Nn * Hout * Hout * C) return;
  unsigned c = idx % C;
  unsigned t = idx / C;
  unsigned ow = t % Hout;
  t /= Hout;
  unsigned oh = t % Hout;
  unsigned n = t / Hout;
  const short* p = y + ((size_t)(n * Hin + oh * 2) * Hin + ow * 2) * C + c;
  int mx = -1000000, mn = 1000000;
#pragma unroll
  for (int kh = 0; kh < 3; ++kh)
#pragma unroll
    for (int kw = 0; kw < 3; ++kw) {
      int v = p[(kh * Hin + kw) * C];
      mx = max(mx, v);
      mn = min(mn, v);
    }
  float sc = par[c];
  float z = (sc >= 0.f ? sc * (float)mx : sc * (float)mn) + par[512 + c];
  o[idx] = (z > 0.f) ? 1 : ((z < 0.f) ? -1 : 0);
}

// sign with S split-K slices summed
__global__ __launch_bounds__(256) void signk(const short* __restrict__ y,
                                             const float* __restrict__ par,
                                             int8_t* __restrict__ o, int total,
                                             int C, int S) {
  unsigned idx = blockIdx.x * 256 + threadIdx.x;
  if (idx >= (unsigned)total) return;
  unsigned c = idx % C;
  int v = 0;
  for (int sl = 0; sl < S; ++sl) v += y[(size_t)sl * total + idx];
  float z = par[c] * (float)v + par[512 + c];
  o[idx] = (z > 0.f) ? 1 : ((z < 0.f) ? -1 : 0);
}

// pool5 over S slices: NHWC i16 [S][8,12,12,256] -> NCHW i8 [8,256,5,5]
__global__ __launch_bounds__(256) void pool5sign_k(const short* __restrict__ y,
                                                   const float* __restrict__ par,
                                                   int8_t* __restrict__ o, int S) {
  unsigned idx = blockIdx.x * 256 + threadIdx.x;
  if (idx >= 8u * 256 * 25) return;
  unsigned ow = idx % 5;
  unsigned t = idx / 5;
  unsigned oh = t % 5;
  t /= 5;
  unsigned c = t % 256, n = t / 256;
  const size_t MN = (size_t)1152 * 256;
  const short* p = y + ((size_t)(n * 12 + oh * 2) * 12 + ow * 2) * 256 + c;
  int mx = -1000000, mn = 1000000;
#pragma unroll
  for (int kh = 0; kh < 3; ++kh)
#pragma unroll
    for (int kw = 0; kw < 3; ++kw) {
      int v = 0;
      for (int sl = 0; sl < S; ++sl) v += p[sl * MN + (kh * 12 + kw) * 256];
      mx = max(mx, v);
      mn = min(mn, v);
    }
  float sc = par[c];
  float z = (sc >= 0.f ? sc * (float)mx : sc * (float)mn) + par[512 + c];
  o[idx] = (z > 0.f) ? 1 : ((z < 0.f) ? -1 : 0);
}

// ---------------------------------------------------------------------------
// weight quantize
// ---------------------------------------------------------------------------
__global__ __launch_bounds__(256) void quantw_k(const float* __restrict__ w,
                                                int8_t* __restrict__ o, int Co,
                                                int Ci, int KHW, int K, int Kp) {
  unsigned idx = blockIdx.x * 256 + threadIdx.x;
  if (idx >= (unsigned)Co * Kp) return;
  unsigned k = idx % Kp;
  unsigned co = idx / Kp;
  int8_t v = 0;
  if (k < (unsigned)K) {
    unsigned tap = k / Ci, ci = k - tap * Ci;
    float f = w[((size_t)co * Ci + ci) * KHW + tap];
    v = (f > 0.f) ? 1 : ((f < 0.f) ? -1 : 0);
  }
  o[idx] = v;
}

__global__ __launch_bounds__(256) void quantwv_k(const float* __restrict__ w,
                                                 int8_t* __restrict__ o,
                                                 unsigned total4) {
  unsigned idx = blockIdx.x * 256 + threadIdx.x;
  if (idx >= total4) return;
  float4 f = ((const float4*)w)[idx];
  union { int8_t b[4]; int i; } u;
  u.b[0] = (f.x > 0.f) ? 1 : ((f.x < 0.f) ? -1 : 0);
  u.b[1] = (f.y > 0.f) ? 1 : ((f.y < 0.f) ? -1 : 0);
  u.b[2] = (f.z > 0.f) ? 1 : ((f.z < 0.f) ? -1 : 0);
  u.b[3] = (f.w > 0.f) ? 1 : ((f.w < 0.f) ? -1 : 0);
  ((int*)o)[idx] = u.i;
}

// ---------------------------------------------------------------------------
// im2col as 16B-chunk vector copy
// ---------------------------------------------------------------------------
__global__ __launch_bounds__(256) void im2colv_k(const int8_t* __restrict__ a,
                                                 int8_t* __restrict__ o, int Nn,
                                                 int H, int C, int KH, int pad,
                                                 int K, int Kp) {
  unsigned t = blockIdx.x * 256 + threadIdx.x;
  unsigned chunks = (unsigned)Kp >> 4;
  unsigned total = (unsigned)Nn * H * H * chunks;
  if (t >= total) return;
  unsigned kc = t % chunks;
  unsigned m = t / chunks;
  unsigned ow = m % H;
  unsigned tmp = m / H;
  unsigned oh = tmp % H;
  unsigned n = tmp / H;
  unsigned k0 = kc << 4;
  int4 v = {0, 0, 0, 0};
  if (k0 < (unsigned)K) {
    unsigned tap = k0 / C;
    unsigned ci = k0 - tap * C;
    unsigned kh = tap / KH, kw = tap - kh * KH;
    int ih = (int)oh - pad + (int)kh, iw = (int)ow - pad + (int)kw;
    if (ih >= 0 && ih < H && iw >= 0 && iw < H)
      v = *(const int4*)(a + (((n * H + ih) * H + iw) * C + ci));
  }
  *(int4*)(o + (size_t)m * Kp + k0) = v;
}

// ---------------------------------------------------------------------------
// i8 GEMM 128x128, BK=64, 16x16x64 MFMA, 4x4 acc (round-4 known-good).
// ---------------------------------------------------------------------------
__global__ __launch_bounds__(256) void gemm_i8_k(const int8_t* __restrict__ A,
                                                 const int8_t* __restrict__ B,
                                                 short* __restrict__ Cm, int M,
                                                 int N, int Kp) {
  __shared__ __align__(16) int8_t As[128 * 64];
  __shared__ __align__(16) int8_t Bs[128 * 64];
  const int tid = threadIdx.x;
  const int lane = tid & 63, wave = tid >> 6;
  const int m0 = blockIdx.x * 128, n0 = blockIdx.y * 128;
  const int wm = (wave >> 1) * 64, wn = (wave & 1) * 64;
  v4i acc[4][4];
#pragma unroll
  for (int r = 0; r < 4; ++r)
#pragma unroll
    for (int u = 0; u < 4; ++u) acc[r][u] = (v4i){0, 0, 0, 0};

  int r_[2], g_[2];
#pragma unroll
  for (int q = 0; q < 2; ++q) {
    int idx = q * 256 + tid;
    r_[q] = idx >> 2;
    g_[q] = (((idx & 3) ^ ((r_[q] >> 1) & 3)) << 4);
  }
  int aoff[4], boff[4];
#pragma unroll
  for (int r = 0; r < 4; ++r) {
    int m = wm + r * 16 + (lane & 15);
    aoff[r] = m * 64 + (((lane >> 4) ^ ((m >> 1) & 3)) << 4);
    int n = wn + r * 16 + (lane & 15);
    boff[r] = n * 64 + (((lane >> 4) ^ ((n >> 1) & 3)) << 4);
  }

  for (int k0 = 0; k0 < Kp; k0 += 64) {
#pragma unroll
    for (int q = 0; q < 2; ++q) {
      int idx = q * 256 + tid;
      g2l16(A + (size_t)(m0 + r_[q]) * Kp + k0 + g_[q], As + idx * 16);
      g2l16(B + (size_t)(n0 + r_[q]) * Kp + k0 + g_[q], Bs + idx * 16);
    }
    __syncthreads();
    v4i af[4], bf[4];
#pragma unroll
    for (int r = 0; r < 4; ++r) {
      af[r] = *(const v4i*)(As + aoff[r]);
      bf[r] = *(const v4i*)(Bs + boff[r]);
    }
#pragma unroll
    for (int r = 0; r < 4; ++r)
#pragma unroll
      for (int u = 0; u < 4; ++u)
        acc[r][u] = __builtin_amdgcn_mfma_i32_16x16x64_i8(af[r], bf[u],
                                                          acc[r][u], 0, 0, 0);
    __syncthreads();
  }
  const int colD = lane & 15, rowD = (lane >> 4) * 4;
#pragma unroll
  for (int r = 0; r < 4; ++r)
#pragma unroll
    for (int u = 0; u < 4; ++u) {
      int n = n0 + wn + u * 16 + colD;
#pragma unroll
      for (int e = 0; e < 4; ++e) {
        int m = m0 + wm + r * 16 + rowD + e;
        if (m < M) Cm[(size_t)m * N + n] = (short)acc[r][u][e];
      }
    }
}

// ---------------------------------------------------------------------------
// i8 GEMM 64x64 tile + split-K over blockIdx.z (conv GEMMs).
// Kslice bytes per slice (multiple of 64); writes to Cm + z*M*N.
// ---------------------------------------------------------------------------
__global__ __launch_bounds__(256) void gemm_i8_64k(const int8_t* __restrict__ A,
                                                   const int8_t* __restrict__ B,
                                                   short* __restrict__ Cm, int M,
                                                   int N, int Kp, int Kslice) {
  __shared__ __align__(16) int8_t As[64 * 64];
  __shared__ __align__(16) int8_t Bs[64 * 64];
  const int tid = threadIdx.x;
  const int lane = tid & 63, wave = tid >> 6;
  const int m0 = blockIdx.x * 64, n0 = blockIdx.y * 64;
  const int kbeg = blockIdx.z * Kslice;
  const int kend = min(kbeg + Kslice, Kp);
  v4i acc[2][2];
#pragma unroll
  for (int r = 0; r < 2; ++r)
#pragma unroll
    for (int u = 0; u < 2; ++u) acc[r][u] = (v4i){0, 0, 0, 0};

  const int wm = (wave >> 1) * 32, wn = (wave & 1) * 32;
  const int rs = tid >> 2;
  const int gsw = (((tid & 3) ^ ((rs >> 1) & 3)) << 4);
  int aoff[2], boff[2];
#pragma unroll
  for (int r = 0; r < 2; ++r) {
    int m = wm + r * 16 + (lane & 15);
    aoff[r] = m * 64 + (((lane >> 4) ^ ((m >> 1) & 3)) << 4);
    int n = wn + r * 16 + (lane & 15);
    boff[r] = n * 64 + (((lane >> 4) ^ ((n >> 1) & 3)) << 4);
  }

  for (int k0 = kbeg; k0 < kend; k0 += 64) {
    g2l16(A + (size_t)(m0 + rs) * Kp + k0 + gsw, As + tid * 16);
    g2l16(B + (size_t)(n0 + rs) * Kp + k0 + gsw, Bs + tid * 16);
    __syncthreads();
    v4i af[2], bf[2];
#pragma unroll
    for (int r = 0; r < 2; ++r) {
      af[r] = *(const v4i*)(As + aoff[r]);
      bf[r] = *(const v4i*)(Bs + boff[r]);
    }
#pragma unroll
    for (int r = 0; r < 2; ++r)
#pragma unroll
      for (int u = 0; u < 2; ++u)
        acc[r][u] = __builtin_amdgcn_mfma_i32_16x16x64_i8(af[r], bf[u],
                                                          acc[r][u], 0, 0, 0);
    __syncthreads();
  }
  short* Cz = Cm + (size_t)blockIdx.z * M * N;
  const int colD = lane & 15, rowD = (lane >> 4) * 4;
#pragma unroll
  for (int r = 0; r < 2; ++r)
#pragma unroll
    for (int u = 0; u < 2; ++u) {
      int n = n0 + wn + u * 16 + colD;
#pragma unroll
      for (int e = 0; e < 4; ++e) {
        int m = m0 + wm + r * 16 + rowD + e;
        if (m < M) Cz[(size_t)m * N + n] = (short)acc[r][u][e];
      }
    }
}

// ---------------------------------------------------------------------------
// f16 GEMM 128x128 (fc3), BK=32 f16 (64 B rows), 16x16x32 MFMA, 4x4 acc.
// ---------------------------------------------------------------------------
__global__ __launch_bounds__(256) void gemm_f16_k(const _Float16* __restrict__ A,
                                                  const _Float16* __restrict__ B,
                                                  float* __restrict__ out,
                                                  const float* __restrict__ bias,
                                                  int M, int Nout, int K) {
  __shared__ __align__(16) int8_t As[128 * 64];
  __shared__ __align__(16) int8_t Bs[128 * 64];
  const int tid = threadIdx.x;
  const int lane = tid & 63, wave = tid >> 6;
  const int m0 = blockIdx.x * 128, n0 = blockIdx.y * 128;
  const int wm = (wave >> 1) * 64, wn = (wave & 1) * 64;
  const int KpB = K * 2;
  v4f acc[4][4];
#pragma unroll
  for (int r = 0; r < 4; ++r)
#pragma unroll
    for (int u = 0; u < 4; ++u) acc[r][u] = (v4f){0.f, 0.f, 0.f, 0.f};

  int r_[2], g_[2];
#pragma unroll
  for (int q = 0; q < 2; ++q) {
    int idx = q * 256 + tid;
    r_[q] = idx >> 2;
    g_[q] = (((idx & 3) ^ ((r_[q] >> 1) & 3)) << 4);
  }
  int aoff[4], boff[4];
#pragma unroll
  for (int r = 0; r < 4; ++r) {
    int m = wm + r * 16 + (lane & 15);
    aoff[r] = m * 64 + (((lane >> 4) ^ ((m >> 1) & 3)) << 4);
    int n = wn + r * 16 + (lane & 15);
    boff[r] = n * 64 + (((lane >> 4) ^ ((n >> 1) & 3)) << 4);
  }

  const int8_t* Ab = (const int8_t*)A;
  const int8_t* Bb = (const int8_t*)B;
  for (int k0 = 0; k0 < KpB; k0 += 64) {
#pragma unroll
    for (int q = 0; q < 2; ++q) {
      int idx = q * 256 + tid;
      g2l16(Ab + (size_t)(m0 + r_[q]) * KpB + k0 + g_[q], As + idx * 16);
      g2l16(Bb + (size_t)(n0 + r_[q]) * KpB + k0 + g_[q], Bs + idx * 16);
    }
    __syncthreads();
    v8h af[4], bf[4];
#pragma unroll
    for (int r = 0; r < 4; ++r) {
      af[r] = *(const v8h*)(As + aoff[r]);
      bf[r] = *(const v8h*)(Bs + boff[r]);
    }
#pragma unroll
    for (int r = 0; r < 4; ++r)
#pragma unroll
      for (int u = 0; u < 4; ++u)
        acc[r][u] = __builtin_amdgcn_mfma_f32_16x16x32_f16(af[r], bf[u],
                                                           acc[r][u], 0, 0, 0);
    __syncthreads();
  }
  const int colD = lane & 15, rowD = (lane >> 4) * 4;
#pragma unroll
  for (int r = 0; r < 4; ++r)
#pragma unroll
    for (int u = 0; u < 4; ++u) {
      int n = n0 + wn + u * 16 + colD;
      if (n < Nout) {
        float bv = bias[n];
#pragma unroll
        for (int e = 0; e < 4; ++e) {
          int m = m0 + wm + r * 16 + rowD + e;
          if (m < M) out[(size_t)m * Nout + n] = acc[r][u][e] + bv;
        }
      }
    }
}

// ---------------------------------------------------------------------------
// fc1 BN6 stats via 5x5 Gram matrix + fused fc1+threshold
// ---------------------------------------------------------------------------
__global__ __launch_bounds__(256) void gram_k(const int8_t* __restrict__ wq1,
                                              int* __restrict__ gm) {
  __shared__ int sg[30];
  if (threadIdx.x < 30) sg[threadIdx.x] = 0;
  __syncthreads();
  int acc[30];
#pragma unroll
  for (int i = 0; i < 30; ++i) acc[i] = 0;
  for (int j = threadIdx.x; j < 4096; j += 256) {
    const int8_t* w = wq1 + j * 5;
    int v[5];
#pragma unroll
    for (int k = 0; k < 5; ++k) v[k] = w[k];
#pragma unroll
    for (int k = 0; k < 5; ++k) {
      acc[k] += v[k];
#pragma unroll
      for (int l = 0; l < 5; ++l) acc[5 + k * 5 + l] += v[k] * v[l];
    }
  }
#pragma unroll
  for (int i = 0; i < 30; ++i) atomicAdd(&sg[i], acc[i]);
  __syncthreads();
  if (threadIdx.x < 30) gm[threadIdx.x] = sg[threadIdx.x];
}

__global__ __launch_bounds__(256) void par6_k(const int8_t* __restrict__ s5,
                                              const int* __restrict__ gm,
                                              const float* __restrict__ g,
                                              const float* __restrict__ bb,
                                              float* __restrict__ par) {
  int c = threadIdx.x;
  long long s = 0, q = 0;
  for (int n = 0; n < 8; ++n)
    for (int i = 0; i < 5; ++i) {
      const int8_t* a = s5 + ((size_t)((n * 256 + c) * 5 + i)) * 5;
      int av[5];
#pragma unroll
      for (int k = 0; k < 5; ++k) av[k] = a[k];
      int ds = 0, dq = 0;
#pragma unroll
      for (int k = 0; k < 5; ++k) {
        ds += av[k] * gm[k];
#pragma unroll
        for (int l = 0; l < 5; ++l) dq += av[k] * av[l] * gm[5 + k * 5 + l];
      }
      s += ds;
      q += dq;
    }
  double P = 163840.0;
  double m = (double)s / P, var = (double)q / P - m * m;
  float inv = (float)(1.0 / sqrt(var + EPS_BN));
  float sc = g[c] * inv;
  par[c] = sc;
  par[512 + c] = bb[c] - (float)m * sc;
}

__global__ __launch_bounds__(256) void fc1f_k(const int8_t* __restrict__ s5,
                                              const int8_t* __restrict__ wq1,
                                              const float* __restrict__ par,
                                              int8_t* __restrict__ f1) {
  unsigned idx = blockIdx.x * 256 + threadIdx.x;
  if (idx >= 10240u * 256) return;
  unsigned m = idx >> 8, jg = idx & 255;
  unsigned c = (m / 5) & 255;
  float sc = par[c], sh = par[512 + c];
  const int8_t* ap = s5 + m * 5;
  int a0 = ap[0], a1 = ap[1], a2 = ap[2], a3 = ap[3], a4 = ap[4];
  int8_t wb[80];
  const int4* wp = (const int4*)(wq1 + jg * 80);
#pragma unroll
  for (int qq = 0; qq < 5; ++qq) *(int4*)(wb + qq * 16) = wp[qq];
  union { int8_t b[16]; int4 v; } ov;
#pragma unroll
  for (int t = 0; t < 16; ++t) {
    int d = a0 * wb[t * 5] + a1 * wb[t * 5 + 1] + a2 * wb[t * 5 + 2] +
            a3 * wb[t * 5 + 3] + a4 * wb[t * 5 + 4];
    float z = sc * (float)d + sh;
    ov.b[t] = (z > 0.f) ? 1 : 0;
  }
  *(int4*)(f1 + (size_t)m * 4096 + jg * 16) = ov.v;
}

// BN7 + relu -> f16, in-place, vectorized x8
__global__ __launch_bounds__(256) void x7v_k(short* __restrict__ f2,
                                             const float* __restrict__ par) {
  unsigned idx = blockIdx.x * 256 + threadIdx.x;
  if (idx >= 10240u * 4096 / 8) return;
  unsigned base8 = idx * 8;
  unsigned c = (base8 / 20480) & 255;
  float sc = par[c], sh = par[512 + c];
  union { int4 v; short s[8]; } in;
  in.v = *(int4*)(f2 + (size_t)base8);
  union { int4 v; _Float16 h[8]; } outv;
#pragma unroll
  for (int t = 0; t < 8; ++t) {
    float z = sc * (float)in.s[t] + sh;
    if (z < 0.f) z = 0.f;
    outv.h[t] = (_Float16)z;
  }
  *(int4*)((_Float16*)f2 + (size_t)base8) = outv.v;
}

__global__ __launch_bounds__(256) void w3h_k(const float* __restrict__ w,
                                             _Float16* __restrict__ o) {
  unsigned idx = blockIdx.x * 256 + threadIdx.x;
  if (idx >= 1024u * 4096) return;
  unsigned j = idx >> 12;
  o[idx] = (j < 1000) ? (_Float16)w[idx] : (_Float16)0.f;
}

// ---------------------------------------------------------------------------
// softmax over dim 1 (256 channels) on [8,256,5,1000] f32, LDS-tiled.
// ---------------------------------------------------------------------------
__global__ __launch_bounds__(256) void softmax_k(float* __restrict__ o) {
  __shared__ float tile[256][33];
  __shared__ float red[8][32];
  __shared__ float mxs[32], invs[32];
  const int bi = blockIdx.x;
  const int jt = blockIdx.y;
  const int b = bi / 5, i = bi % 5;
  float* base = o + ((size_t)(b * 256) * 5 + i) * 1000;
  const int t = threadIdx.x;
  const int jl = t & 31, part = t >> 5;
  const int j = jt * 32 + jl;
  const bool ok = (j < 1000);
  for (int cg = 0; cg < 32; ++cg) {
    int c = cg * 8 + part;
    tile[c][jl] = ok ? base[(size_t)c * 5000 + j] : 0.f;
  }
  __syncthreads();
  float pm = -1e30f;
#pragma unroll 4
  for (int cc = 0; cc < 32; ++cc) pm = fmaxf(pm, tile[part * 32 + cc][jl]);
  red[part][jl] = pm;
  __syncthreads();
  if (part == 0) {
    float m = red[0][jl];
#pragma unroll
    for (int p = 1; p < 8; ++p) m = fmaxf(m, red[p][jl]);
    mxs[jl] = m;
  }
  __syncthreads();
  float mx = mxs[jl];
  float ps = 0.f;
#pragma unroll 4
  for (int cc = 0; cc < 32; ++cc) ps += expf(tile[part * 32 + cc][jl] - mx);
  red[part][jl] = ps;
  __syncthreads();
  if (part == 0) {
    float s = red[0][jl];
#pragma unroll
    for (int p = 1; p < 8; ++p) s += red[p][jl];
    invs[jl] = 1.f / s;
  }
  __syncthreads();
  float inv = invs[jl];
  for (int cg = 0; cg < 32; ++cg) {
    int c = cg * 8 + part;
    if (ok) base[(size_t)c * 5000 + j] = expf(tile[c][jl] - mx) * inv;
  }
}

// ---------------------------------------------------------------------------
// launcher
// ---------------------------------------------------------------------------
static inline unsigned gs(size_t n) { return (unsigned)((n + 255) / 256); }

extern "C" void kernel_launch(void* const* d_in, const int* in_sizes, int n_in,
                              void* d_out, int out_size, void* d_ws,
                              size_t ws_size, hipStream_t stream) {
  (void)in_sizes; (void)n_in; (void)out_size; (void)ws_size;
  const float* x    = (const float*)d_in[0];
  const float* w1   = (const float*)d_in[1];
  const float* bn1g = (const float*)d_in[3];
  const float* bn1b = (const float*)d_in[4];
  const float* w2   = (const float*)d_in[5];
  const float* bn2g = (const float*)d_in[7];
  const float* bn2b = (const float*)d_in[8];
  const float* w3   = (const float*)d_in[9];
  const float* bn3g = (const float*)d_in[11];
  const float* bn3b = (const float*)d_in[12];
  const float* w4   = (const float*)d_in[13];
  const float* bn4g = (const float*)d_in[15];
  const float* bn4b = (const float*)d_in[16];
  const float* w5   = (const float*)d_in[17];
  const float* bn5g = (const float*)d_in[19];
  const float* bn5b = (const float*)d_in[20];
  const float* fc1w = (const float*)d_in[21];
  const float* bn6g = (const float*)d_in[22];
  const float* bn6b = (const float*)d_in[23];
  const float* fc2w = (const float*)d_in[24];
  const float* bn7g = (const float*)d_in[25];
  const float* bn7b = (const float*)d_in[26];
  const float* fc3w = (const float*)d_in[27];
  const float* fc3b = (const float*)d_in[28];
  float* out = (float*)d_out;

  char* ws = (char*)d_ws;
  size_t off = 0;
  auto alloc = [&](size_t bytes) -> void* {
    off = (off + 255) & ~(size_t)255;
    void* p = ws + off;
    off += bytes;
    return p;
  };
  float*   Y1   = (float*)alloc((size_t)8 * 96 * 51 * 51 * 4);
  int8_t*  S1   = (int8_t*)alloc((size_t)8 * 25 * 25 * 96);
  int8_t*  IM   = (int8_t*)alloc((size_t)5120 * 2432);
  short*   Y2   = (short*)alloc((size_t)5056 * 256 * 2);
  int8_t*  S2   = (int8_t*)alloc((size_t)1152 * 256);
  short*   Y3   = (short*)alloc((size_t)1152 * 384 * 2 * 4);   // 4 K-slices
  int8_t*  S3   = (int8_t*)alloc((size_t)1152 * 384);
  short*   Y4   = (short*)alloc((size_t)1152 * 384 * 2 * 3);   // 3 K-slices
  int8_t*  S4   = (int8_t*)alloc((size_t)1152 * 384);
  short*   Y5   = (short*)alloc((size_t)1152 * 256 * 2 * 3);   // 3 K-slices
  int8_t*  S5   = (int8_t*)alloc((size_t)8 * 256 * 25);
  int8_t*  WQ2  = (int8_t*)alloc((size_t)256 * 2432);
  int8_t*  WQ3  = (int8_t*)alloc((size_t)384 * 2304);
  int8_t*  WQ4  = (int8_t*)alloc((size_t)384 * 3456);
  int8_t*  WQ5  = (int8_t*)alloc((size_t)256 * 3456);
  int8_t*  WQ1  = (int8_t*)alloc((size_t)4096 * 5);
  int8_t*  WQF2 = (int8_t*)alloc((size_t)4096 * 4096);
  int8_t*  F1   = (int8_t*)alloc((size_t)10240 * 4096);
  short*   F2   = (short*)alloc((size_t)10240 * 4096 * 2);
  _Float16* W3H = (_Float16*)alloc((size_t)1024 * 4096 * 2);
  float*   PAR  = (float*)alloc((size_t)7 * 1024 * 4);
  int*     GM   = (int*)alloc(32 * 4);
  double*  PART = (double*)alloc((size_t)2048 * 2 * 8);
  float* par1 = PAR;
  float* par2 = PAR + 1024;
  float* par3 = PAR + 2048;
  float* par4 = PAR + 3072;
  float* par5 = PAR + 4096;
  float* par6 = PAR + 5120;
  float* par7 = PAR + 6144;

  // ---- weight prep ----
  quantw_k<<<gs((size_t)256 * 2432), 256, 0, stream>>>(w2, WQ2, 256, 96, 25, 2400, 2432);
  quantw_k<<<gs((size_t)384 * 2304), 256, 0, stream>>>(w3, WQ3, 384, 256, 9, 2304, 2304);
  quantw_k<<<gs((size_t)384 * 3456), 256, 0, stream>>>(w4, WQ4, 384, 384, 9, 3456, 3456);
  quantw_k<<<gs((size_t)256 * 3456), 256, 0, stream>>>(w5, WQ5, 256, 384, 9, 3456, 3456);
  quantw_k<<<gs((size_t)4096 * 5), 256, 0, stream>>>(fc1w, WQ1, 4096, 5, 1, 5, 5);
  quantwv_k<<<gs((size_t)4096 * 1024), 256, 0, stream>>>(fc2w, WQF2, 4096u * 1024);
  w3h_k<<<gs((size_t)1024 * 4096), 256, 0, stream>>>(fc3w, W3H);

  // ---- conv1 + BN1 + relu + pool + sign ----
  conv1_k<<<dim3(8 * 51, 6), 256, 0, stream>>>(x, w1, Y1);
  bnstat_nchw_k<float><<<dim3(96), 256, 0, stream>>>(Y1, bn1g, bn1b, par1, 96, 2601, 8);
  pool1sign_k<<<gs((size_t)8 * 96 * 625), 256, 0, stream>>>(Y1, par1, S1);

  // ---- conv2 (no split-K: 316 blocks already) ----
  im2colv_k<<<gs((size_t)5000 * 152), 256, 0, stream>>>(S1, IM, 8, 25, 96, 5, 2, 2400, 2432);
  gemm_i8_64k<<<dim3(79, 4, 1), 256, 0, stream>>>(IM, WQ2, Y2, 5000, 256, 2432, 2432);
  bnstat_nhwc_k<<<dim3(256), 256, 0, stream>>>(Y2, bn2g, bn2b, par2, 256, 5000, 1);
  poolsign_k<<<gs((size_t)8 * 144 * 256), 256, 0, stream>>>(Y2, par2, S2, 8, 25, 256, 12);

  // ---- conv3 (split-K 4: 2304 = 4 x 576) ----
  im2colv_k<<<gs((size_t)1152 * 144), 256, 0, stream>>>(S2, IM, 8, 12, 256, 3, 1, 2304, 2304);
  gemm_i8_64k<<<dim3(18, 6, 4), 256, 0, stream>>>(IM, WQ3, Y3, 1152, 384, 2304, 576);
  bnstat_nhwc_k<<<dim3(384), 256, 0, stream>>>(Y3, bn3g, bn3b, par3, 384, 1152, 4);
  signk<<<gs((size_t)1152 * 384), 256, 0, stream>>>(Y3, par3, S3, 1152 * 384, 384, 4);

  // ---- conv4 (split-K 3: 3456 = 3 x 1152) ----
  im2colv_k<<<gs((size_t)1152 * 216), 256, 0, stream>>>(S3, IM, 8, 12, 384, 3, 1, 3456, 3456);
  gemm_i8_64k<<<dim3(18, 6, 3), 256, 0, stream>>>(IM, WQ4, Y4, 1152, 384, 3456, 1152);
  bnstat_nhwc_k<<<dim3(384), 256, 0, stream>>>(Y4, bn4g, bn4b, par4, 384, 1152, 3);
  signk<<<gs((size_t)1152 * 384), 256, 0, stream>>>(Y4, par4, S4, 1152 * 384, 384, 3);

  // ---- conv5 (split-K 3) ----
  im2colv_k<<<gs((size_t)1152 * 216), 256, 0, stream>>>(S4, IM, 8, 12, 384, 3, 1, 3456, 3456);
  gemm_i8_64k<<<dim3(18, 4, 3), 256, 0, stream>>>(IM, WQ5, Y5, 1152, 256, 3456, 1152);
  bnstat_nhwc_k<<<dim3(256), 256, 0, stream>>>(Y5, bn5g, bn5b, par5, 256, 1152, 3);
  pool5sign_k<<<gs((size_t)8 * 256 * 25), 256, 0, stream>>>(Y5, par5, S5, 3);

  // ---- fc1 ----
  gram_k<<<dim3(1), 256, 0, stream>>>(WQ1, GM);
  par6_k<<<dim3(1), 256, 0, stream>>>(S5, GM, bn6g, bn6b, par6);
  fc1f_k<<<gs((size_t)10240 * 256), 256, 0, stream>>>(S5, WQ1, par6, F1);

  // ---- fc2 ----
  gemm_i8_k<<<dim3(80, 32), 256, 0, stream>>>(F1, WQF2, F2, 10240, 4096, 4096);
  bnp16_k<<<dim3(256, 8), 256, 0, stream>>>(F2, PART);
  bnf7_k<<<dim3(1), 256, 0, stream>>>(PART, bn7g, bn7b, par7);
  x7v_k<<<gs((size_t)10240 * 512), 256, 0, stream>>>(F2, par7);

  // ---- fc3 + softmax ----
  gemm_f16_k<<<dim3(80, 8), 256, 0, stream>>>((const _Float16*)F2, W3H, out, fc3b,
                                              10240, 1000, 4096);
  softmax_k<<<dim3(40, 32), 256, 0, stream>>>(out);
}